// Round 13
// baseline (143.450 us; speedup 1.0000x reference)
//
#include <hip/hip_runtime.h>
#include <type_traits>

typedef short bf16x8 __attribute__((ext_vector_type(8)));
typedef float f32x4 __attribute__((ext_vector_type(4)));

// ---------------- problem constants ----------------
constexpr int Hh = 14, Ww = 14, Cc = 512, Bb = 512, NR = 70, PadR = 80;
constexpr int MROWS = 72;   // LDS rows for m: 70 data + 2 zero rows (72..79 remapped)

// ---------------- constexpr replication of _crop_boxes ----------------
struct Box { int y1, y2, x1, x2; };

constexpr double cfloor(double v) { return (double)(long long)v; }  // v >= 0 only
constexpr double cround(double v) {  // np.round: half-to-even
    double f = cfloor(v);
    double fr = v - f;
    if (fr > 0.5) return f + 1.0;
    if (fr < 0.5) return f;
    return (((long long)f) & 1LL) ? f + 1.0 : f;
}

struct BoxArr { Box b[NR]; };

constexpr BoxArr make_boxes() {
    BoxArr out{};
    double rx_[14] = {}, ry_[14] = {}, wl_[14] = {};
    int nr = 0;
    for (int l = 1; l <= 3; ++l) {
        double wl  = cfloor(2.0 * 14.0 / (double)(l + 1));
        double wl2 = cfloor(wl / 2.0 - 1.0);
        double bb  = (l > 1) ? (14.0 - wl) / (double)(l - 1) : 0.0;
        double cen[3] = {};
        for (int k = 0; k < l; ++k) cen[k] = cfloor(wl2 + (double)k * bb) - wl2;
        for (int i = 0; i < l; ++i)
            for (int j = 0; j < l; ++j) { rx_[nr] = cen[j]; ry_[nr] = cen[i]; wl_[nr] = wl; ++nr; }
    }
    int nb = 0;
    for (int r = 0; r < nr; ++r) {
        for (int p = 1; p <= 2; ++p) {
            double len = wl_[r] / (double)p;
            for (int ix = 0; ix < p; ++ix)
                for (int jy = 0; jy < p; ++jy) {
                    int x1 = (int)cround(rx_[r] + ix * len);
                    int x2 = (int)cround(rx_[r] + ix * len + len);
                    int y1 = (int)cround(ry_[r] + jy * len);
                    int y2 = (int)cround(ry_[r] + jy * len + len);
                    out.b[nb] = Box{y1, y2, x1, x2};
                    ++nb;
                }
        }
    }
    return out;
}
constexpr BoxArr BOXES = make_boxes();

// distinct x-interval dedup
struct Meta { int nxi; int xlo[32]; int xhi[32]; int xid[NR]; };
constexpr Meta make_meta() {
    Meta m{};
    m.nxi = 0;
    for (int r = 0; r < NR; ++r) {
        int lo = BOXES.b[r].x1, hi = BOXES.b[r].x2, id = -1;
        for (int i = 0; i < m.nxi; ++i) if (m.xlo[i] == lo && m.xhi[i] == hi) { id = i; break; }
        if (id < 0) { id = m.nxi; m.xlo[id] = lo; m.xhi[id] = hi; m.nxi++; }
        m.xid[r] = id;
    }
    return m;
}
constexpr Meta MT = make_meta();
constexpr int NXI = MT.nxi;
static_assert(NXI == 14, "expected 14 distinct x-intervals");

// per-h box lists (boxes whose [y1,y2) contains h) -- register y-fold
struct HRows { int cnt[Hh]; int idx[Hh][40]; };
constexpr HRows make_hb() {
    HRows hb{};
    for (int h = 0; h < Hh; ++h) {
        hb.cnt[h] = 0;
        for (int r = 0; r < NR; ++r)
            if (BOXES.b[r].y1 <= h && h < BOXES.b[r].y2) {
                hb.idx[h][hb.cnt[h]] = r;
                hb.cnt[h]++;
            }
    }
    return hb;
}
constexpr HRows HB = make_hb();
constexpr int hb_max() { int m = 0; for (int h = 0; h < Hh; ++h) m = HB.cnt[h] > m ? HB.cnt[h] : m; return m; }
static_assert(hb_max() <= 40, "HB idx array too small");

// is box r the FIRST of its pack-pair (r, r^1) to retire?  (ties: even first)
constexpr bool pair_first(int r) {
    int o = r ^ 1;
    int y2r = BOXES.b[r].y2, y2o = BOXES.b[o].y2;
    if (y2r != y2o) return y2r < y2o;
    return (r & 1) == 0;
}

__device__ __forceinline__ ushort f2bf(float f) {  // RNE float->bf16 (finite; -inf ok)
    union { float f; unsigned u; } v; v.f = f;
    unsigned r = v.u + 0x7FFFu + ((v.u >> 16) & 1u);
    return (ushort)(r >> 16);
}
__device__ __forceinline__ float bf2f(ushort u) {
    union { unsigned u; float f; } v; v.u = ((unsigned)u) << 16;
    return v.f;
}

// swizzled index into m_s[*][512]: 16B slots XOR'd by row&15 (4-bit spread)
__device__ __forceinline__ int midx(int r, int c) {
    return r * Cc + (((c >> 3) ^ (r & 15)) << 3) + (c & 7);
}

// async global -> LDS, 16 B per lane (fire-and-forget, counted by vmcnt)
__device__ __forceinline__ void gload_lds16(const void* g, void* l) {
    __builtin_amdgcn_global_load_lds(
        (const __attribute__((address_space(1))) unsigned int*)g,
        (__attribute__((address_space(3))) unsigned int*)l,
        16, 0, 0);
}

// ---------------- kernel 0: W fp32 -> bf16 ----------------
__global__ __launch_bounds__(256) void k_convw(const float* __restrict__ w,
                                               ushort* __restrict__ o) {
    int i = (blockIdx.x * 256 + threadIdx.x) * 4;
    float4 f = *(const float4*)&w[i];
    ushort4 u;
    u.x = f2bf(f.x); u.y = f2bf(f.y); u.z = f2bf(f.z); u.w = f2bf(f.w);
    *(ushort4*)&o[i] = u;
}

// ---------------- fused: 2 images/block, cross-image pipelining ------------------
// Block p handles images b0=2p, b1=2p+1 (grid 256 = 1 block/CU, ONE round).
// GEMM(b0)'s 8 ks-steps are embedded into pool(b1)'s 14 fold iterations: MFMA on
// m_s(b0) rides under pool(b1)'s DMA waits + VALU folds (disjoint LDS + regs).
// Counted vmcnt per in-order retirement: h<=7 -> 12 (8 B-loads + 4 next-row DMA
// newer than row h), h=8..12 -> 4, h=13 -> 0. Numerics verbatim R9/R10.
__global__ __launch_bounds__(512) void k_fused(const float* __restrict__ x,
                                               const ushort* __restrict__ wbf,
                                               const float* __restrict__ bias,
                                               float* __restrict__ out) {
    __shared__ __align__(16) float xbuf[2][Ww * Cc];         // 56 KB stream ring
    __shared__ __align__(16) union MU {
        ushort m_s[MROWS * Cc];                              // 72 KB
        struct {                                             // epilogue scratch
            float rowss[PadR][8];
            float rns[PadR];
            float y_s[Cc];
            float red2[8];
        } e;
    } mu;
    __shared__ float ss_a[PadR], ss_b[PadR];

    const int p = blockIdx.x;
    const int b0 = 2 * p, b1 = 2 * p + 1;
    const int tid = threadIdx.x;
    const int lane = tid & 63;
    const int wv = tid >> 6;                // 0..7
    const int l15 = lane & 15, lhi = lane >> 4;

    if (tid >= 70 && tid < PadR) { ss_a[tid] = 0.f; ss_b[tid] = 0.f; }

    const char* xA = (const char*)(x + (size_t)b0 * (Hh * Ww * Cc));
    const char* xB = (const char*)(x + (size_t)b1 * (Hh * Ww * Cc));

    // issue one image row (28672 B) into xbuf[h&1]: waves 0..6, 4 x 16B each
    auto issueRow = [&](const char* xb, int h) {
        if (tid < 448) {
            const char* src = xb + (size_t)h * (Ww * Cc * 4);
            char* dst = (char*)xbuf[h & 1];
            #pragma unroll
            for (int i = 0; i < 4; ++i) {
                const int off = i * 7168 + tid * 16;
                gload_lds16(src + off, dst + off);
            }
        }
    };

    float acc70[NR];
    uint pk[NR / 2];

    // ================= pool b0 (R9 exact: depth-2 ring, counted waits) =========
    issueRow(xA, 0); issueRow(xA, 1);
    #pragma unroll
    for (int h = 0; h < Hh; ++h) {
        if (h < Hh - 1) asm volatile("s_waitcnt vmcnt(4)" ::: "memory");
        else            asm volatile("s_waitcnt vmcnt(0)" ::: "memory");
        __builtin_amdgcn_s_barrier();

        float row[Ww];
        #pragma unroll
        for (int w = 0; w < Ww; ++w) row[w] = xbuf[h & 1][w * Cc + tid];
        float rmx[NXI];
        #pragma unroll
        for (int xi = 0; xi < NXI; ++xi) {
            float mm = row[MT.xlo[xi]];
            #pragma unroll
            for (int w = MT.xlo[xi] + 1; w < MT.xhi[xi]; ++w) mm = fmaxf(mm, row[w]);
            rmx[xi] = mm;
        }
        #pragma unroll
        for (int bi = 0; bi < HB.cnt[h]; ++bi) {
            const int r = HB.idx[h][bi];
            const float v = rmx[MT.xid[r]];
            acc70[r] = (BOXES.b[r].y1 == h) ? v : fmaxf(acc70[r], v);
        }
        __builtin_amdgcn_s_barrier();
        if (h + 2 < Hh) issueRow(xA, h + 2);
    }

    // start b1's stream immediately (hides under handoff+SS)
    issueRow(xB, 0); issueRow(xB, 1);

    // ---- handoff a: acc70 -> m_s (b0); zero pad rows 70,71 ----
    {
        uint* z = (uint*)&mu.m_s[70 * Cc];
        z[tid] = 0;
        #pragma unroll
        for (int r = 0; r < NR; ++r) mu.m_s[midx(r, tid)] = f2bf(acc70[r]);
    }
    asm volatile("s_waitcnt lgkmcnt(0)" ::: "memory");   // LDS-only barrier
    __builtin_amdgcn_s_barrier();

    // ---- SS(b0) -> ss_a ----
    #pragma unroll
    for (int i = 0; i < 9; ++i) {
        const int rr = wv * 9 + i;
        if (rr < NR) {
            float s = 0.f;
            #pragma unroll
            for (int cg = 0; cg < 4; ++cg) {
                ushort2 t2 = *(const ushort2*)&mu.m_s[midx(rr, cg * 128 + 2 * lane)];
                float m0 = bf2f(t2.x), m1 = bf2f(t2.y);
                s += m0 * m0 + m1 * m1;
            }
            s += __shfl_xor(s, 1);  s += __shfl_xor(s, 2);  s += __shfl_xor(s, 4);
            s += __shfl_xor(s, 8);  s += __shfl_xor(s, 16); s += __shfl_xor(s, 32);
            if (lane == 0) ss_a[rr] = s;
        }
    }
    asm volatile("s_waitcnt lgkmcnt(0)" ::: "memory");
    __builtin_amdgcn_s_barrier();

    // ================= pool b1 with GEMM(b0) ks-steps embedded ================
    f32x4 acc[5][4];
    #pragma unroll
    for (int mi = 0; mi < 5; ++mi)
        #pragma unroll
        for (int ni = 0; ni < 4; ++ni) acc[mi][ni] = (f32x4){0.f, 0.f, 0.f, 0.f};

    auto loadB = [&](bf16x8 (&bf)[4][2], int k0) {
        #pragma unroll
        for (int ni = 0; ni < 4; ++ni)
            #pragma unroll
            for (int kh = 0; kh < 2; ++kh)
                bf[ni][kh] = *(const bf16x8*)(wbf + (size_t)(wv * 64 + ni * 16 + l15) * Cc
                                              + k0 + kh * 32 + lhi * 8);
    };

    bf16x8 bfc[4][2], bfn[4][2];
    loadB(bfc, 0);

    #pragma unroll
    for (int h = 0; h < Hh; ++h) {
        // wait for row h only (in-order vmcnt retirement; see header comment)
        if      (h <= 7)  asm volatile("s_waitcnt vmcnt(12)" ::: "memory");
        else if (h <= 12) asm volatile("s_waitcnt vmcnt(4)"  ::: "memory");
        else              asm volatile("s_waitcnt vmcnt(0)"  ::: "memory");
        __builtin_amdgcn_s_barrier();

        // fold row h of b1 (R10's packed retirement)
        float row[Ww];
        #pragma unroll
        for (int w = 0; w < Ww; ++w) row[w] = xbuf[h & 1][w * Cc + tid];
        float rmx[NXI];
        #pragma unroll
        for (int xi = 0; xi < NXI; ++xi) {
            float mm = row[MT.xlo[xi]];
            #pragma unroll
            for (int w = MT.xlo[xi] + 1; w < MT.xhi[xi]; ++w) mm = fmaxf(mm, row[w]);
            rmx[xi] = mm;
        }
        #pragma unroll
        for (int bi = 0; bi < HB.cnt[h]; ++bi) {
            const int r = HB.idx[h][bi];
            const float v = rmx[MT.xid[r]];
            acc70[r] = (BOXES.b[r].y1 == h) ? v : fmaxf(acc70[r], v);
            if (BOXES.b[r].y2 == h + 1) {
                const uint q = (uint)f2bf(acc70[r]);
                const uint qs = (r & 1) ? (q << 16) : q;
                if (pair_first(r)) pk[r >> 1] = qs;
                else               pk[r >> 1] |= qs;
            }
        }

        // embedded GEMM(b0) step ks = h (reads m_s, disjoint from xbuf)
        if (h < 8) {
            if (h < 7) loadB(bfn, (h + 1) * 64);
            #pragma unroll
            for (int kh = 0; kh < 2; ++kh) {
                bf16x8 af[5];
                #pragma unroll
                for (int mi = 0; mi < 5; ++mi) {
                    int row_ = mi * 16 + l15;
                    int rc = (mi < 4) ? row_
                                      : ((row_ < MROWS) ? row_ : (70 | (row_ & 1)));
                    int slot = (h * 8 + kh * 4 + lhi) ^ (rc & 15);
                    af[mi] = *(const bf16x8*)&mu.m_s[rc * Cc + slot * 8];
                }
                #pragma unroll
                for (int mi = 0; mi < 5; ++mi)
                    #pragma unroll
                    for (int ni = 0; ni < 4; ++ni)
                        acc[mi][ni] = __builtin_amdgcn_mfma_f32_16x16x32_bf16(
                            af[mi], bfc[ni][kh], acc[mi][ni], 0, 0, 0);
            }
            if (h < 7) {
                #pragma unroll
                for (int ni = 0; ni < 4; ++ni)
                    #pragma unroll
                    for (int kh = 0; kh < 2; ++kh) bfc[ni][kh] = bfn[ni][kh];
            }
        }

        __builtin_amdgcn_s_barrier();        // all folds of xbuf[h&1] done
        if (h + 2 < Hh) issueRow(xB, h + 2);
    }
    // here: vmcnt drained (h=13 waited 0); GEMM(b0) complete; pk holds m(b1)

    // ================= epilogue(b0) -> out(b0) (scratch aliases m_s) ==========
    {
        float bia[4];
        #pragma unroll
        for (int ni = 0; ni < 4; ++ni) bia[ni] = bias[wv * 64 + ni * 16 + l15];
        float rm[5][4];
        #pragma unroll
        for (int mi = 0; mi < 5; ++mi)
            #pragma unroll
            for (int j = 0; j < 4; ++j)
                rm[mi][j] = 1.f / fmaxf(sqrtf(ss_a[mi * 16 + lhi * 4 + j]), 1e-12f);
        #pragma unroll
        for (int mi = 0; mi < 5; ++mi)
            #pragma unroll
            for (int ni = 0; ni < 4; ++ni)
                #pragma unroll
                for (int j = 0; j < 4; ++j)
                    acc[mi][ni][j] = fmaf(acc[mi][ni][j], rm[mi][j], bia[ni]);

        __syncthreads();                     // m_s reads (GEMM) done; alias OK
        #pragma unroll
        for (int mi = 0; mi < 5; ++mi)
            #pragma unroll
            for (int j = 0; j < 4; ++j) {
                float s = 0.f;
                #pragma unroll
                for (int ni = 0; ni < 4; ++ni) s += acc[mi][ni][j] * acc[mi][ni][j];
                s += __shfl_xor(s, 1); s += __shfl_xor(s, 2);
                s += __shfl_xor(s, 4); s += __shfl_xor(s, 8);
                if (l15 == 0) mu.e.rowss[mi * 16 + lhi * 4 + j][wv] = s;
            }
        __syncthreads();
        if (tid < PadR) {
            float s = 0.f;
            #pragma unroll
            for (int w8 = 0; w8 < 8; ++w8) s += mu.e.rowss[tid][w8];
            mu.e.rns[tid] = 1.f / fmaxf(sqrtf(s), 1e-12f);
        }
        __syncthreads();

        float ys[4] = {0.f, 0.f, 0.f, 0.f};
        #pragma unroll
        for (int mi = 0; mi < 5; ++mi)
            #pragma unroll
            for (int j = 0; j < 4; ++j) {
                int row_ = mi * 16 + lhi * 4 + j;
                float w = (row_ < NR) ? mu.e.rns[row_] : 0.f;
                #pragma unroll
                for (int ni = 0; ni < 4; ++ni) ys[ni] = fmaf(acc[mi][ni][j], w, ys[ni]);
            }
        #pragma unroll
        for (int ni = 0; ni < 4; ++ni) {
            ys[ni] += __shfl_xor(ys[ni], 16);
            ys[ni] += __shfl_xor(ys[ni], 32);
        }
        if (lane < 16)
            #pragma unroll
            for (int ni = 0; ni < 4; ++ni) mu.e.y_s[wv * 64 + ni * 16 + lane] = ys[ni];
        __syncthreads();

        float yv = mu.e.y_s[tid];
        float s2 = yv * yv;
        s2 += __shfl_xor(s2, 1);  s2 += __shfl_xor(s2, 2);  s2 += __shfl_xor(s2, 4);
        s2 += __shfl_xor(s2, 8);  s2 += __shfl_xor(s2, 16); s2 += __shfl_xor(s2, 32);
        if (lane == 0) mu.e.red2[wv] = s2;
        __syncthreads();
        float tot = 0.f;
        #pragma unroll
        for (int w8 = 0; w8 < 8; ++w8) tot += mu.e.red2[w8];
        out[(size_t)b0 * Cc + tid] = yv / fmaxf(sqrtf(tot), 1e-12f);
    }
    __syncthreads();                         // scratch reads done before handoff b

    // ================= handoff b: pk -> m_s; SS(b1); GEMM(b1); epilogue =======
    {
        uint* z = (uint*)&mu.m_s[70 * Cc];
        z[tid] = 0;
        #pragma unroll
        for (int r = 0; r < NR; ++r) {
            const ushort q = (r & 1) ? (ushort)(pk[r >> 1] >> 16)
                                     : (ushort)(pk[r >> 1] & 0xFFFFu);
            mu.m_s[midx(r, tid)] = q;
        }
    }
    __syncthreads();

    #pragma unroll
    for (int i = 0; i < 9; ++i) {
        const int rr = wv * 9 + i;
        if (rr < NR) {
            float s = 0.f;
            #pragma unroll
            for (int cg = 0; cg < 4; ++cg) {
                ushort2 t2 = *(const ushort2*)&mu.m_s[midx(rr, cg * 128 + 2 * lane)];
                float m0 = bf2f(t2.x), m1 = bf2f(t2.y);
                s += m0 * m0 + m1 * m1;
            }
            s += __shfl_xor(s, 1);  s += __shfl_xor(s, 2);  s += __shfl_xor(s, 4);
            s += __shfl_xor(s, 8);  s += __shfl_xor(s, 16); s += __shfl_xor(s, 32);
            if (lane == 0) ss_b[rr] = s;
        }
    }
    __syncthreads();

    #pragma unroll
    for (int mi = 0; mi < 5; ++mi)
        #pragma unroll
        for (int ni = 0; ni < 4; ++ni) acc[mi][ni] = (f32x4){0.f, 0.f, 0.f, 0.f};

    loadB(bfc, 0);
    #pragma unroll
    for (int ks = 0; ks < 8; ++ks) {
        if (ks < 7) loadB(bfn, (ks + 1) * 64);
        #pragma unroll
        for (int kh = 0; kh < 2; ++kh) {
            bf16x8 af[5];
            #pragma unroll
            for (int mi = 0; mi < 5; ++mi) {
                int row_ = mi * 16 + l15;
                int rc = (mi < 4) ? row_
                                  : ((row_ < MROWS) ? row_ : (70 | (row_ & 1)));
                int slot = (ks * 8 + kh * 4 + lhi) ^ (rc & 15);
                af[mi] = *(const bf16x8*)&mu.m_s[rc * Cc + slot * 8];
            }
            #pragma unroll
            for (int mi = 0; mi < 5; ++mi)
                #pragma unroll
                for (int ni = 0; ni < 4; ++ni)
                    acc[mi][ni] = __builtin_amdgcn_mfma_f32_16x16x32_bf16(
                        af[mi], bfc[ni][kh], acc[mi][ni], 0, 0, 0);
        }
        #pragma unroll
        for (int ni = 0; ni < 4; ++ni)
            #pragma unroll
            for (int kh = 0; kh < 2; ++kh) bfc[ni][kh] = bfn[ni][kh];
    }
    __syncthreads();

    {
        float bia[4];
        #pragma unroll
        for (int ni = 0; ni < 4; ++ni) bia[ni] = bias[wv * 64 + ni * 16 + l15];
        float rm[5][4];
        #pragma unroll
        for (int mi = 0; mi < 5; ++mi)
            #pragma unroll
            for (int j = 0; j < 4; ++j)
                rm[mi][j] = 1.f / fmaxf(sqrtf(ss_b[mi * 16 + lhi * 4 + j]), 1e-12f);
        #pragma unroll
        for (int mi = 0; mi < 5; ++mi)
            #pragma unroll
            for (int ni = 0; ni < 4; ++ni)
                #pragma unroll
                for (int j = 0; j < 4; ++j)
                    acc[mi][ni][j] = fmaf(acc[mi][ni][j], rm[mi][j], bia[ni]);

        #pragma unroll
        for (int mi = 0; mi < 5; ++mi)
            #pragma unroll
            for (int j = 0; j < 4; ++j) {
                float s = 0.f;
                #pragma unroll
                for (int ni = 0; ni < 4; ++ni) s += acc[mi][ni][j] * acc[mi][ni][j];
                s += __shfl_xor(s, 1); s += __shfl_xor(s, 2);
                s += __shfl_xor(s, 4); s += __shfl_xor(s, 8);
                if (l15 == 0) mu.e.rowss[mi * 16 + lhi * 4 + j][wv] = s;
            }
        __syncthreads();
        if (tid < PadR) {
            float s = 0.f;
            #pragma unroll
            for (int w8 = 0; w8 < 8; ++w8) s += mu.e.rowss[tid][w8];
            mu.e.rns[tid] = 1.f / fmaxf(sqrtf(s), 1e-12f);
        }
        __syncthreads();

        float ys[4] = {0.f, 0.f, 0.f, 0.f};
        #pragma unroll
        for (int mi = 0; mi < 5; ++mi)
            #pragma unroll
            for (int j = 0; j < 4; ++j) {
                int row_ = mi * 16 + lhi * 4 + j;
                float w = (row_ < NR) ? mu.e.rns[row_] : 0.f;
                #pragma unroll
                for (int ni = 0; ni < 4; ++ni) ys[ni] = fmaf(acc[mi][ni][j], w, ys[ni]);
            }
        #pragma unroll
        for (int ni = 0; ni < 4; ++ni) {
            ys[ni] += __shfl_xor(ys[ni], 16);
            ys[ni] += __shfl_xor(ys[ni], 32);
        }
        if (lane < 16)
            #pragma unroll
            for (int ni = 0; ni < 4; ++ni) mu.e.y_s[wv * 64 + ni * 16 + lane] = ys[ni];
        __syncthreads();

        float yv = mu.e.y_s[tid];
        float s2 = yv * yv;
        s2 += __shfl_xor(s2, 1);  s2 += __shfl_xor(s2, 2);  s2 += __shfl_xor(s2, 4);
        s2 += __shfl_xor(s2, 8);  s2 += __shfl_xor(s2, 16); s2 += __shfl_xor(s2, 32);
        if (lane == 0) mu.e.red2[wv] = s2;
        __syncthreads();
        float tot = 0.f;
        #pragma unroll
        for (int w8 = 0; w8 < 8; ++w8) tot += mu.e.red2[w8];
        out[(size_t)b1 * Cc + tid] = yv / fmaxf(sqrtf(tot), 1e-12f);
    }
}

// ---------------- launch ----------------
extern "C" void kernel_launch(void* const* d_in, const int* in_sizes, int n_in,
                              void* d_out, int out_size, void* d_ws, size_t ws_size,
                              hipStream_t stream) {
    const float* x  = (const float*)d_in[0];
    const float* pw = (const float*)d_in[1];
    const float* pb = (const float*)d_in[2];
    float* out = (float*)d_out;

    ushort* wbf = (ushort*)d_ws;                          // 512x512 bf16 = 0.5 MB

    k_convw<<<dim3(256), dim3(256), 0, stream>>>(pw, wbf);
    k_fused<<<dim3(Bb / 2), dim3(512), 0, stream>>>(x, wbf, pb, out);
}

// Round 14
// 89.062 us; speedup vs baseline: 1.6107x; 1.6107x over previous
//
#include <hip/hip_runtime.h>
#include <type_traits>

typedef short bf16x8 __attribute__((ext_vector_type(8)));
typedef float f32x4 __attribute__((ext_vector_type(4)));

// ---------------- problem constants ----------------
constexpr int Hh = 14, Ww = 14, Cc = 512, Bb = 512, NR = 70, PadR = 80;
constexpr int MROWS = 72;   // LDS rows for m: 70 data + 2 zero rows (72..79 remapped)

// ---------------- constexpr replication of _crop_boxes ----------------
struct Box { int y1, y2, x1, x2; };

constexpr double cfloor(double v) { return (double)(long long)v; }  // v >= 0 only
constexpr double cround(double v) {  // np.round: half-to-even
    double f = cfloor(v);
    double fr = v - f;
    if (fr > 0.5) return f + 1.0;
    if (fr < 0.5) return f;
    return (((long long)f) & 1LL) ? f + 1.0 : f;
}

struct BoxArr { Box b[NR]; };

constexpr BoxArr make_boxes() {
    BoxArr out{};
    double rx_[14] = {}, ry_[14] = {}, wl_[14] = {};
    int nr = 0;
    for (int l = 1; l <= 3; ++l) {
        double wl  = cfloor(2.0 * 14.0 / (double)(l + 1));
        double wl2 = cfloor(wl / 2.0 - 1.0);
        double bb  = (l > 1) ? (14.0 - wl) / (double)(l - 1) : 0.0;
        double cen[3] = {};
        for (int k = 0; k < l; ++k) cen[k] = cfloor(wl2 + (double)k * bb) - wl2;
        for (int i = 0; i < l; ++i)
            for (int j = 0; j < l; ++j) { rx_[nr] = cen[j]; ry_[nr] = cen[i]; wl_[nr] = wl; ++nr; }
    }
    int nb = 0;
    for (int r = 0; r < nr; ++r) {
        for (int p = 1; p <= 2; ++p) {
            double len = wl_[r] / (double)p;
            for (int ix = 0; ix < p; ++ix)
                for (int jy = 0; jy < p; ++jy) {
                    int x1 = (int)cround(rx_[r] + ix * len);
                    int x2 = (int)cround(rx_[r] + ix * len + len);
                    int y1 = (int)cround(ry_[r] + jy * len);
                    int y2 = (int)cround(ry_[r] + jy * len + len);
                    out.b[nb] = Box{y1, y2, x1, x2};
                    ++nb;
                }
        }
    }
    return out;
}
constexpr BoxArr BOXES = make_boxes();

// distinct x-interval dedup
struct Meta { int nxi; int xlo[32]; int xhi[32]; int xid[NR]; };
constexpr Meta make_meta() {
    Meta m{};
    m.nxi = 0;
    for (int r = 0; r < NR; ++r) {
        int lo = BOXES.b[r].x1, hi = BOXES.b[r].x2, id = -1;
        for (int i = 0; i < m.nxi; ++i) if (m.xlo[i] == lo && m.xhi[i] == hi) { id = i; break; }
        if (id < 0) { id = m.nxi; m.xlo[id] = lo; m.xhi[id] = hi; m.nxi++; }
        m.xid[r] = id;
    }
    return m;
}
constexpr Meta MT = make_meta();
constexpr int NXI = MT.nxi;
static_assert(NXI == 14, "expected 14 distinct x-intervals");

// per-h box lists (boxes whose [y1,y2) contains h) -- register y-fold
struct HRows { int cnt[Hh]; int idx[Hh][40]; };
constexpr HRows make_hb() {
    HRows hb{};
    for (int h = 0; h < Hh; ++h) {
        hb.cnt[h] = 0;
        for (int r = 0; r < NR; ++r)
            if (BOXES.b[r].y1 <= h && h < BOXES.b[r].y2) {
                hb.idx[h][hb.cnt[h]] = r;
                hb.cnt[h]++;
            }
    }
    return hb;
}
constexpr HRows HB = make_hb();
constexpr int hb_max() { int m = 0; for (int h = 0; h < Hh; ++h) m = HB.cnt[h] > m ? HB.cnt[h] : m; return m; }
static_assert(hb_max() <= 40, "HB idx array too small");

// is box r the FIRST of its pack-pair (r, r^1) to retire?  (ties: even first)
constexpr bool pair_first(int r) {
    int o = r ^ 1;
    int y2r = BOXES.b[r].y2, y2o = BOXES.b[o].y2;
    if (y2r != y2o) return y2r < y2o;
    return (r & 1) == 0;
}

__device__ __forceinline__ ushort f2bf(float f) {  // RNE float->bf16 (finite; -inf ok)
    union { float f; unsigned u; } v; v.f = f;
    unsigned r = v.u + 0x7FFFu + ((v.u >> 16) & 1u);
    return (ushort)(r >> 16);
}
__device__ __forceinline__ float bf2f(ushort u) {
    union { unsigned u; float f; } v; v.u = ((unsigned)u) << 16;
    return v.f;
}

// swizzled index into m_s[*][512]: 16B slots XOR'd by row&15 (4-bit spread)
__device__ __forceinline__ int midx(int r, int c) {
    return r * Cc + (((c >> 3) ^ (r & 15)) << 3) + (c & 7);
}

// async global -> LDS, 16 B per lane (fire-and-forget, counted by vmcnt)
__device__ __forceinline__ void gload_lds16(const void* g, void* l) {
    __builtin_amdgcn_global_load_lds(
        (const __attribute__((address_space(1))) unsigned int*)g,
        (__attribute__((address_space(3))) unsigned int*)l,
        16, 0, 0);
}

// ---------------- kernel 0: W fp32 -> bf16 ----------------
__global__ __launch_bounds__(256) void k_convw(const float* __restrict__ w,
                                               ushort* __restrict__ o) {
    int i = (blockIdx.x * 256 + threadIdx.x) * 4;
    float4 f = *(const float4*)&w[i];
    ushort4 u;
    u.x = f2bf(f.x); u.y = f2bf(f.y); u.z = f2bf(f.z); u.w = f2bf(f.w);
    *(ushort4*)&o[i] = u;
}

// ---------------- fused: direct-to-LDS streamed pooling -> GEMM ------------------
// R10 structure (gload_lds row streaming, xbuf/m_s union, packed bf16 retirement)
// with the register budget FIXED: __launch_bounds__(512, 2) declares min-occupancy
// half of R9/R10's "4" -> VGPR cap 128 instead of 64 (the "4" was budgeted as
// 8 waves/SIMD = 64 VGPRs -> 20-30 MB of scratch spill on the fold critical path,
// R9-R11 evidence). Still declares a min so the dispatcher co-schedules 2 blocks/CU
// (74 KB LDS x 2 fits 160 KB; R9 got 40% occupancy with a hint, R7 without = 22%).
__global__ __launch_bounds__(512, 2)
void k_fused(const float* __restrict__ x,
             const ushort* __restrict__ wbf,
             const float* __restrict__ bias,
             float* __restrict__ out) {
    __shared__ __align__(16) union UU {
        float xbuf[2][Ww * Cc];                      // 2 x 28 KB row buffers
        ushort m_s[MROWS * Cc];                      // 72 KB (union = 72 KB)
    } u;
    __shared__ float ss_s[PadR];

    struct EScratch {                                // aliases m_s post-GEMM
        float rowss[PadR][8];
        float rns[PadR];
        float y_s[Cc];
        float red2[8];
    };
    EScratch* sc = (EScratch*)u.m_s;

    const int b = blockIdx.x;
    const int tid = threadIdx.x;
    const int lane = tid & 63;
    const int wv = tid >> 6;                // 0..7
    const int l15 = lane & 15, lhi = lane >> 4;

    if (tid >= 70 && tid < PadR) ss_s[tid] = 0.f;

    const char* xb = (const char*)(x + (size_t)b * (Hh * Ww * Cc));

    // issue one image row (28672 B) into xbuf[h&1]: waves 0..6, 4 x 16B each
    auto issueRow = [&](int h) {
        if (tid < 448) {
            const char* src = xb + (size_t)h * (Ww * Cc * 4);
            char* dst = (char*)u.xbuf[h & 1];
            #pragma unroll
            for (int i = 0; i < 4; ++i) {
                const int off = i * 7168 + tid * 16;
                gload_lds16(src + off, dst + off);
            }
        }
    };

    float acc70[NR];                         // live only between birth and retire
    uint  pk[NR / 2];                        // retired boxes, 2 bf16 per uint

    issueRow(0);
    __syncthreads();                         // row 0 resident (vmcnt(0) drain)

    #pragma unroll
    for (int h = 0; h < Hh; ++h) {
        if (h + 1 < Hh) issueRow(h + 1);     // stream next row under this fold
        // fold row h from LDS: thread = channel tid
        float row[Ww];
        #pragma unroll
        for (int w = 0; w < Ww; ++w) row[w] = u.xbuf[h & 1][w * Cc + tid];
        float rmx[NXI];
        #pragma unroll
        for (int xi = 0; xi < NXI; ++xi) {
            float mm = row[MT.xlo[xi]];
            #pragma unroll
            for (int w = MT.xlo[xi] + 1; w < MT.xhi[xi]; ++w) mm = fmaxf(mm, row[w]);
            rmx[xi] = mm;
        }
        #pragma unroll
        for (int bi = 0; bi < HB.cnt[h]; ++bi) {
            const int r = HB.idx[h][bi];                     // compile-time
            const float v = rmx[MT.xid[r]];
            acc70[r] = (BOXES.b[r].y1 == h) ? v : fmaxf(acc70[r], v);
            if (BOXES.b[r].y2 == h + 1) {                    // retire: quantize+pack
                const uint q = (uint)f2bf(acc70[r]);
                const uint qs = (r & 1) ? (q << 16) : q;
                if (pair_first(r)) pk[r >> 1] = qs;          // full overwrite (first)
                else               pk[r >> 1] |= qs;         // other half already set
            }
        }
        __syncthreads();                     // next row's loads drained; buf reusable
    }

    // ---- handoff: m_s aliases xbuf (all reads done); unpack packed bf16 ----
    {
        uint* z = (uint*)&u.m_s[70 * Cc];
        z[tid] = 0;                          // zero rows 70,71 (512 uints)
        #pragma unroll
        for (int r = 0; r < NR; ++r) {
            const ushort q = (r & 1) ? (ushort)(pk[r >> 1] >> 16)
                                     : (ushort)(pk[r >> 1] & 0xFFFFu);
            u.m_s[midx(r, tid)] = q;
        }
    }
    __syncthreads();                         // m_s complete

    // ---- SS from m_s (same read/accumulate order as previous rounds) ----
    #pragma unroll
    for (int i = 0; i < 9; ++i) {
        const int rr = wv * 9 + i;
        if (rr < NR) {
            float s = 0.f;
            #pragma unroll
            for (int cg = 0; cg < 4; ++cg) {
                ushort2 t2 = *(const ushort2*)&u.m_s[midx(rr, cg * 128 + 2 * lane)];
                float m0 = bf2f(t2.x), m1 = bf2f(t2.y);
                s += m0 * m0 + m1 * m1;
            }
            s += __shfl_xor(s, 1);  s += __shfl_xor(s, 2);  s += __shfl_xor(s, 4);
            s += __shfl_xor(s, 8);  s += __shfl_xor(s, 16); s += __shfl_xor(s, 32);
            if (lane == 0) ss_s[rr] = s;
        }
    }
    __syncthreads();                         // ss_s ready

    // ---- GEMM: t[80][512] = m * W^T, A resident in m_s, no barriers ----
    f32x4 acc[5][4];
    #pragma unroll
    for (int mi = 0; mi < 5; ++mi)
        #pragma unroll
        for (int ni = 0; ni < 4; ++ni) acc[mi][ni] = (f32x4){0.f, 0.f, 0.f, 0.f};

    auto loadB = [&](bf16x8 (&bf)[4][2], int k0) {
        #pragma unroll
        for (int ni = 0; ni < 4; ++ni)
            #pragma unroll
            for (int kh = 0; kh < 2; ++kh)
                bf[ni][kh] = *(const bf16x8*)(wbf + (size_t)(wv * 64 + ni * 16 + l15) * Cc
                                              + k0 + kh * 32 + lhi * 8);
    };

    bf16x8 bfc[4][2], bfn[4][2];
    loadB(bfc, 0);
    #pragma unroll
    for (int ks = 0; ks < 8; ++ks) {
        if (ks < 7) loadB(bfn, (ks + 1) * 64);
        #pragma unroll
        for (int kh = 0; kh < 2; ++kh) {
            bf16x8 af[5];
            #pragma unroll
            for (int mi = 0; mi < 5; ++mi) {
                int row_ = mi * 16 + l15;
                // rows 72..79 don't exist in LDS: remap to zero rows 70/71
                int rc = (mi < 4) ? row_
                                  : ((row_ < MROWS) ? row_ : (70 | (row_ & 1)));
                int slot = (ks * 8 + kh * 4 + lhi) ^ (rc & 15);
                af[mi] = *(const bf16x8*)&u.m_s[rc * Cc + slot * 8];
            }
            #pragma unroll
            for (int mi = 0; mi < 5; ++mi)
                #pragma unroll
                for (int ni = 0; ni < 4; ++ni)
                    acc[mi][ni] = __builtin_amdgcn_mfma_f32_16x16x32_bf16(
                        af[mi], bfc[ni][kh], acc[mi][ni], 0, 0, 0);
        }
        #pragma unroll
        for (int ni = 0; ni < 4; ++ni)
            #pragma unroll
            for (int kh = 0; kh < 2; ++kh) bfc[ni][kh] = bfn[ni][kh];
    }
    __syncthreads();                          // m_s reads done; epilogue may alias

    // ---- fused epilogue: deferred A-norm + bias, row-norm, sum, final norm ----
    float bia[4];
    #pragma unroll
    for (int ni = 0; ni < 4; ++ni) bia[ni] = bias[wv * 64 + ni * 16 + l15];
    float rm[5][4];
    #pragma unroll
    for (int mi = 0; mi < 5; ++mi)
        #pragma unroll
        for (int j = 0; j < 4; ++j)
            rm[mi][j] = 1.f / fmaxf(sqrtf(ss_s[mi * 16 + lhi * 4 + j]), 1e-12f);
    #pragma unroll
    for (int mi = 0; mi < 5; ++mi)
        #pragma unroll
        for (int ni = 0; ni < 4; ++ni)
            #pragma unroll
            for (int j = 0; j < 4; ++j)
                acc[mi][ni][j] = fmaf(acc[mi][ni][j], rm[mi][j], bia[ni]);

    #pragma unroll
    for (int mi = 0; mi < 5; ++mi)
        #pragma unroll
        for (int j = 0; j < 4; ++j) {
            float s = 0.f;
            #pragma unroll
            for (int ni = 0; ni < 4; ++ni) s += acc[mi][ni][j] * acc[mi][ni][j];
            s += __shfl_xor(s, 1); s += __shfl_xor(s, 2);
            s += __shfl_xor(s, 4); s += __shfl_xor(s, 8);
            if (l15 == 0) sc->rowss[mi * 16 + lhi * 4 + j][wv] = s;
        }
    __syncthreads();
    if (tid < PadR) {
        float s = 0.f;
        #pragma unroll
        for (int w8 = 0; w8 < 8; ++w8) s += sc->rowss[tid][w8];
        sc->rns[tid] = 1.f / fmaxf(sqrtf(s), 1e-12f);
    }
    __syncthreads();

    float ys[4] = {0.f, 0.f, 0.f, 0.f};
    #pragma unroll
    for (int mi = 0; mi < 5; ++mi)
        #pragma unroll
        for (int j = 0; j < 4; ++j) {
            int row_ = mi * 16 + lhi * 4 + j;
            float w = (row_ < NR) ? sc->rns[row_] : 0.f;   // skip pad rows
            #pragma unroll
            for (int ni = 0; ni < 4; ++ni) ys[ni] = fmaf(acc[mi][ni][j], w, ys[ni]);
        }
    #pragma unroll
    for (int ni = 0; ni < 4; ++ni) {
        ys[ni] += __shfl_xor(ys[ni], 16);
        ys[ni] += __shfl_xor(ys[ni], 32);
    }
    if (lane < 16)
        #pragma unroll
        for (int ni = 0; ni < 4; ++ni) sc->y_s[wv * 64 + ni * 16 + lane] = ys[ni];
    __syncthreads();

    float yv = sc->y_s[tid];
    float s2 = yv * yv;
    s2 += __shfl_xor(s2, 1);  s2 += __shfl_xor(s2, 2);  s2 += __shfl_xor(s2, 4);
    s2 += __shfl_xor(s2, 8);  s2 += __shfl_xor(s2, 16); s2 += __shfl_xor(s2, 32);
    if (lane == 0) sc->red2[wv] = s2;
    __syncthreads();
    float tot = 0.f;
    #pragma unroll
    for (int w8 = 0; w8 < 8; ++w8) tot += sc->red2[w8];
    out[(size_t)b * Cc + tid] = yv / fmaxf(sqrtf(tot), 1e-12f);
}

// ---------------- launch ----------------
extern "C" void kernel_launch(void* const* d_in, const int* in_sizes, int n_in,
                              void* d_out, int out_size, void* d_ws, size_t ws_size,
                              hipStream_t stream) {
    const float* x  = (const float*)d_in[0];
    const float* pw = (const float*)d_in[1];
    const float* pb = (const float*)d_in[2];
    float* out = (float*)d_out;

    ushort* wbf = (ushort*)d_ws;                          // 512x512 bf16 = 0.5 MB

    k_convw<<<dim3(256), dim3(256), 0, stream>>>(pw, wbf);
    k_fused<<<dim3(Bb), dim3(512), 0, stream>>>(x, wbf, pb, out);
}

// Round 15
// 84.054 us; speedup vs baseline: 1.7066x; 1.0596x over previous
//
#include <hip/hip_runtime.h>
#include <type_traits>

typedef short bf16x8 __attribute__((ext_vector_type(8)));
typedef float f32x4 __attribute__((ext_vector_type(4)));

// ---------------- problem constants ----------------
constexpr int Hh = 14, Ww = 14, Cc = 512, Bb = 512, NR = 70, PadR = 80;
constexpr int MROWS = 72;   // LDS rows for m: 70 data + 2 zero rows (72..79 remapped)

// ---------------- constexpr replication of _crop_boxes ----------------
struct Box { int y1, y2, x1, x2; };

constexpr double cfloor(double v) { return (double)(long long)v; }  // v >= 0 only
constexpr double cround(double v) {  // np.round: half-to-even
    double f = cfloor(v);
    double fr = v - f;
    if (fr > 0.5) return f + 1.0;
    if (fr < 0.5) return f;
    return (((long long)f) & 1LL) ? f + 1.0 : f;
}

struct BoxArr { Box b[NR]; };

constexpr BoxArr make_boxes() {
    BoxArr out{};
    double rx_[14] = {}, ry_[14] = {}, wl_[14] = {};
    int nr = 0;
    for (int l = 1; l <= 3; ++l) {
        double wl  = cfloor(2.0 * 14.0 / (double)(l + 1));
        double wl2 = cfloor(wl / 2.0 - 1.0);
        double bb  = (l > 1) ? (14.0 - wl) / (double)(l - 1) : 0.0;
        double cen[3] = {};
        for (int k = 0; k < l; ++k) cen[k] = cfloor(wl2 + (double)k * bb) - wl2;
        for (int i = 0; i < l; ++i)
            for (int j = 0; j < l; ++j) { rx_[nr] = cen[j]; ry_[nr] = cen[i]; wl_[nr] = wl; ++nr; }
    }
    int nb = 0;
    for (int r = 0; r < nr; ++r) {
        for (int p = 1; p <= 2; ++p) {
            double len = wl_[r] / (double)p;
            for (int ix = 0; ix < p; ++ix)
                for (int jy = 0; jy < p; ++jy) {
                    int x1 = (int)cround(rx_[r] + ix * len);
                    int x2 = (int)cround(rx_[r] + ix * len + len);
                    int y1 = (int)cround(ry_[r] + jy * len);
                    int y2 = (int)cround(ry_[r] + jy * len + len);
                    out.b[nb] = Box{y1, y2, x1, x2};
                    ++nb;
                }
        }
    }
    return out;
}
constexpr BoxArr BOXES = make_boxes();

// distinct x-interval dedup
struct Meta { int nxi; int xlo[32]; int xhi[32]; int xid[NR]; };
constexpr Meta make_meta() {
    Meta m{};
    m.nxi = 0;
    for (int r = 0; r < NR; ++r) {
        int lo = BOXES.b[r].x1, hi = BOXES.b[r].x2, id = -1;
        for (int i = 0; i < m.nxi; ++i) if (m.xlo[i] == lo && m.xhi[i] == hi) { id = i; break; }
        if (id < 0) { id = m.nxi; m.xlo[id] = lo; m.xhi[id] = hi; m.nxi++; }
        m.xid[r] = id;
    }
    return m;
}
constexpr Meta MT = make_meta();
constexpr int NXI = MT.nxi;
static_assert(NXI == 14, "expected 14 distinct x-intervals");

// per-h box lists (boxes whose [y1,y2) contains h) -- register y-fold
struct HRows { int cnt[Hh]; int idx[Hh][40]; };
constexpr HRows make_hb() {
    HRows hb{};
    for (int h = 0; h < Hh; ++h) {
        hb.cnt[h] = 0;
        for (int r = 0; r < NR; ++r)
            if (BOXES.b[r].y1 <= h && h < BOXES.b[r].y2) {
                hb.idx[h][hb.cnt[h]] = r;
                hb.cnt[h]++;
            }
    }
    return hb;
}
constexpr HRows HB = make_hb();
constexpr int hb_max() { int m = 0; for (int h = 0; h < Hh; ++h) m = HB.cnt[h] > m ? HB.cnt[h] : m; return m; }
static_assert(hb_max() <= 40, "HB idx array too small");

__device__ __forceinline__ ushort f2bf(float f) {  // RNE float->bf16 (finite; -inf ok)
    union { float f; unsigned u; } v; v.f = f;
    unsigned r = v.u + 0x7FFFu + ((v.u >> 16) & 1u);
    return (ushort)(r >> 16);
}
__device__ __forceinline__ float bf2f(ushort u) {
    union { unsigned u; float f; } v; v.u = ((unsigned)u) << 16;
    return v.f;
}

// swizzled index into m_s[*][512]: 16B slots XOR'd by row&7 (matches GEMM read)
__device__ __forceinline__ int midx(int r, int c) {
    return r * Cc + (((c >> 3) ^ (r & 7)) << 3) + (c & 7);
}

// async global -> LDS, 16 B per lane (fire-and-forget, counted by vmcnt)
__device__ __forceinline__ void gload_lds16(const void* g, void* l) {
    __builtin_amdgcn_global_load_lds(
        (const __attribute__((address_space(1))) unsigned int*)g,
        (__attribute__((address_space(3))) unsigned int*)l,
        16, 0, 0);
}

// ---------------- kernel 0: W fp32 -> bf16 ----------------
__global__ __launch_bounds__(256) void k_convw(const float* __restrict__ w,
                                               ushort* __restrict__ o) {
    int i = (blockIdx.x * 256 + threadIdx.x) * 4;
    float4 f = *(const float4*)&w[i];
    ushort4 u;
    u.x = f2bf(f.x); u.y = f2bf(f.y); u.z = f2bf(f.z); u.w = f2bf(f.w);
    *(ushort4*)&o[i] = u;
}

// ---------------- fused: direct-to-LDS streamed pooling -> GEMM ------------------
// BEST-MEASURED CONFIGURATION (round 9, 84.5 us) -- resubmitted verbatim.
// Per row-step h: issue row h+1 (28 KB) via global_load_lds width-16 bursts (deep
// VMEM queue, no VGPR round-trip), fold row h from LDS (14 conflict-free
// ds_read_b32/thread) into register accumulators. __syncthreads per step = the
// depth-1 pipeline drain. xbuf[2] (56 KB) unions with m_s (72 KB).
// Note: __launch_bounds__(512,4) caps arch VGPRs at 64 -> ~19 MB accumulator
// spill (measured ~free) AND enables 2 co-resident blocks/CU (occupancy ~40%),
// which is worth ~4% -- the best measured trade (R9 vs R12/R14 A/B).
__global__ __launch_bounds__(512, 4) void k_fused(const float* __restrict__ x,
                                                  const ushort* __restrict__ wbf,
                                                  const float* __restrict__ bias,
                                                  float* __restrict__ out) {
    __shared__ __align__(16) union UU {
        float xbuf[2][Ww * Cc];                      // 2 x 28 KB row buffers
        ushort m_s[MROWS * Cc];                      // 72 KB (union = 72 KB)
    } u;
    __shared__ float ss_s[PadR];

    struct EScratch {                                // aliases m_s post-GEMM
        float rowss[PadR][8];
        float rns[PadR];
        float y_s[Cc];
        float red2[8];
    };
    EScratch* sc = (EScratch*)u.m_s;

    const int b = blockIdx.x;
    const int tid = threadIdx.x;
    const int lane = tid & 63;
    const int wv = tid >> 6;                // 0..7
    const int l15 = lane & 15, lhi = lane >> 4;

    if (tid >= 70 && tid < PadR) ss_s[tid] = 0.f;

    const char* xb = (const char*)(x + (size_t)b * (Hh * Ww * Cc));

    // issue one image row (28672 B) into xbuf[h&1]: waves 0..6, 4 x 16B each
    auto issueRow = [&](int h) {
        if (tid < 448) {
            const char* src = xb + (size_t)h * (Ww * Cc * 4);
            char* dst = (char*)u.xbuf[h & 1];
            #pragma unroll
            for (int i = 0; i < 4; ++i) {
                const int off = i * 7168 + tid * 16;
                gload_lds16(src + off, dst + off);
            }
        }
    };

    float acc70[NR];                         // live-range managed (birth at y1)

    issueRow(0);
    __syncthreads();                         // row 0 resident (vmcnt(0) drain)

    #pragma unroll
    for (int h = 0; h < Hh; ++h) {
        if (h + 1 < Hh) issueRow(h + 1);     // stream next row under this fold
        // fold row h from LDS: thread = channel tid
        float row[Ww];
        #pragma unroll
        for (int w = 0; w < Ww; ++w) row[w] = u.xbuf[h & 1][w * Cc + tid];
        float rmx[NXI];
        #pragma unroll
        for (int xi = 0; xi < NXI; ++xi) {
            float mm = row[MT.xlo[xi]];
            #pragma unroll
            for (int w = MT.xlo[xi] + 1; w < MT.xhi[xi]; ++w) mm = fmaxf(mm, row[w]);
            rmx[xi] = mm;
        }
        #pragma unroll
        for (int bi = 0; bi < HB.cnt[h]; ++bi) {
            const int r = HB.idx[h][bi];                     // compile-time
            const float v = rmx[MT.xid[r]];
            acc70[r] = (BOXES.b[r].y1 == h) ? v : fmaxf(acc70[r], v);
        }
        __syncthreads();                     // next row's loads drained; buf reusable
    }

    // ---- handoff: m_s aliases xbuf (all reads done); quantize once ----
    {
        uint* z = (uint*)&u.m_s[70 * Cc];
        z[tid] = 0;                          // zero rows 70,71 (512 uints)
        #pragma unroll
        for (int r = 0; r < NR; ++r) u.m_s[midx(r, tid)] = f2bf(acc70[r]);
    }
    __syncthreads();                         // m_s complete

    // ---- SS from m_s (same read/accumulate order as previous rounds) ----
    #pragma unroll
    for (int i = 0; i < 9; ++i) {
        const int rr = wv * 9 + i;
        if (rr < NR) {
            float s = 0.f;
            #pragma unroll
            for (int cg = 0; cg < 4; ++cg) {
                ushort2 t2 = *(const ushort2*)&u.m_s[midx(rr, cg * 128 + 2 * lane)];
                float m0 = bf2f(t2.x), m1 = bf2f(t2.y);
                s += m0 * m0 + m1 * m1;
            }
            s += __shfl_xor(s, 1);  s += __shfl_xor(s, 2);  s += __shfl_xor(s, 4);
            s += __shfl_xor(s, 8);  s += __shfl_xor(s, 16); s += __shfl_xor(s, 32);
            if (lane == 0) ss_s[rr] = s;
        }
    }
    __syncthreads();                         // ss_s ready

    // ---- GEMM: t[80][512] = m * W^T, A resident in m_s, no barriers ----
    f32x4 acc[5][4];
    #pragma unroll
    for (int mi = 0; mi < 5; ++mi)
        #pragma unroll
        for (int ni = 0; ni < 4; ++ni) acc[mi][ni] = (f32x4){0.f, 0.f, 0.f, 0.f};

    auto loadB = [&](bf16x8 (&bf)[4][2], int k0) {
        #pragma unroll
        for (int ni = 0; ni < 4; ++ni)
            #pragma unroll
            for (int kh = 0; kh < 2; ++kh)
                bf[ni][kh] = *(const bf16x8*)(wbf + (size_t)(wv * 64 + ni * 16 + l15) * Cc
                                              + k0 + kh * 32 + lhi * 8);
    };

    bf16x8 bfc[4][2], bfn[4][2];
    loadB(bfc, 0);
    #pragma unroll
    for (int ks = 0; ks < 8; ++ks) {
        if (ks < 7) loadB(bfn, (ks + 1) * 64);
        #pragma unroll
        for (int kh = 0; kh < 2; ++kh) {
            bf16x8 af[5];
            #pragma unroll
            for (int mi = 0; mi < 5; ++mi) {
                int row_ = mi * 16 + l15;
                // rows 72..79 don't exist in LDS: remap to zero rows 70/71
                int rc = (mi < 4) ? row_
                                  : ((row_ < MROWS) ? row_ : (70 | (row_ & 1)));
                int slot = (ks * 8 + kh * 4 + lhi) ^ (rc & 7);
                af[mi] = *(const bf16x8*)&u.m_s[rc * Cc + slot * 8];
            }
            #pragma unroll
            for (int mi = 0; mi < 5; ++mi)
                #pragma unroll
                for (int ni = 0; ni < 4; ++ni)
                    acc[mi][ni] = __builtin_amdgcn_mfma_f32_16x16x32_bf16(
                        af[mi], bfc[ni][kh], acc[mi][ni], 0, 0, 0);
        }
        #pragma unroll
        for (int ni = 0; ni < 4; ++ni)
            #pragma unroll
            for (int kh = 0; kh < 2; ++kh) bfc[ni][kh] = bfn[ni][kh];
    }
    __syncthreads();                          // m_s reads done; epilogue may alias

    // ---- fused epilogue: deferred A-norm + bias, row-norm, sum, final norm ----
    float bia[4];
    #pragma unroll
    for (int ni = 0; ni < 4; ++ni) bia[ni] = bias[wv * 64 + ni * 16 + l15];
    float rm[5][4];
    #pragma unroll
    for (int mi = 0; mi < 5; ++mi)
        #pragma unroll
        for (int j = 0; j < 4; ++j)
            rm[mi][j] = 1.f / fmaxf(sqrtf(ss_s[mi * 16 + lhi * 4 + j]), 1e-12f);
    #pragma unroll
    for (int mi = 0; mi < 5; ++mi)
        #pragma unroll
        for (int ni = 0; ni < 4; ++ni)
            #pragma unroll
            for (int j = 0; j < 4; ++j)
                acc[mi][ni][j] = fmaf(acc[mi][ni][j], rm[mi][j], bia[ni]);

    #pragma unroll
    for (int mi = 0; mi < 5; ++mi)
        #pragma unroll
        for (int j = 0; j < 4; ++j) {
            float s = 0.f;
            #pragma unroll
            for (int ni = 0; ni < 4; ++ni) s += acc[mi][ni][j] * acc[mi][ni][j];
            s += __shfl_xor(s, 1); s += __shfl_xor(s, 2);
            s += __shfl_xor(s, 4); s += __shfl_xor(s, 8);
            if (l15 == 0) sc->rowss[mi * 16 + lhi * 4 + j][wv] = s;
        }
    __syncthreads();
    if (tid < PadR) {
        float s = 0.f;
        #pragma unroll
        for (int w8 = 0; w8 < 8; ++w8) s += sc->rowss[tid][w8];
        sc->rns[tid] = 1.f / fmaxf(sqrtf(s), 1e-12f);
    }
    __syncthreads();

    float ys[4] = {0.f, 0.f, 0.f, 0.f};
    #pragma unroll
    for (int mi = 0; mi < 5; ++mi)
        #pragma unroll
        for (int j = 0; j < 4; ++j) {
            int row_ = mi * 16 + lhi * 4 + j;
            float w = (row_ < NR) ? sc->rns[row_] : 0.f;   // skip pad rows
            #pragma unroll
            for (int ni = 0; ni < 4; ++ni) ys[ni] = fmaf(acc[mi][ni][j], w, ys[ni]);
        }
    #pragma unroll
    for (int ni = 0; ni < 4; ++ni) {
        ys[ni] += __shfl_xor(ys[ni], 16);
        ys[ni] += __shfl_xor(ys[ni], 32);
    }
    if (lane < 16)
        #pragma unroll
        for (int ni = 0; ni < 4; ++ni) sc->y_s[wv * 64 + ni * 16 + lane] = ys[ni];
    __syncthreads();

    float yv = sc->y_s[tid];
    float s2 = yv * yv;
    s2 += __shfl_xor(s2, 1);  s2 += __shfl_xor(s2, 2);  s2 += __shfl_xor(s2, 4);
    s2 += __shfl_xor(s2, 8);  s2 += __shfl_xor(s2, 16); s2 += __shfl_xor(s2, 32);
    if (lane == 0) sc->red2[wv] = s2;
    __syncthreads();
    float tot = 0.f;
    #pragma unroll
    for (int w8 = 0; w8 < 8; ++w8) tot += sc->red2[w8];
    out[(size_t)b * Cc + tid] = yv / fmaxf(sqrtf(tot), 1e-12f);
}

// ---------------- launch ----------------
extern "C" void kernel_launch(void* const* d_in, const int* in_sizes, int n_in,
                              void* d_out, int out_size, void* d_ws, size_t ws_size,
                              hipStream_t stream) {
    const float* x  = (const float*)d_in[0];
    const float* pw = (const float*)d_in[1];
    const float* pb = (const float*)d_in[2];
    float* out = (float*)d_out;

    ushort* wbf = (ushort*)d_ws;                          // 512x512 bf16 = 0.5 MB

    k_convw<<<dim3(256), dim3(256), 0, stream>>>(pw, wbf);
    k_fused<<<dim3(Bb), dim3(512), 0, stream>>>(x, wbf, pb, out);
}